// Round 8
// baseline (672.486 us; speedup 1.0000x reference)
//
#include <hip/hip_runtime.h>
#include <hip/hip_bf16.h>

#define T_TOK 4096
#define HID   1024
#define INTER 2048
#define NE    8
#define NE1   9      // 8 routed + 1 shared expert
#define BK    64     // K-tile for g2 (unchanged, verified)
#define MAXT  104    // max 128-row m-tiles: <=72 routed + 32 shared

typedef __attribute__((ext_vector_type(8))) short short8;
typedef __attribute__((ext_vector_type(8))) unsigned short ushort8v;
typedef __attribute__((ext_vector_type(4))) float f32x4;

__device__ __forceinline__ unsigned short f2bf(float f) {
    __hip_bfloat16 h = __float2bfloat16(f);
    return __builtin_bit_cast(unsigned short, h);
}
__device__ __forceinline__ float bf2f(unsigned short u) {
    unsigned int v = ((unsigned int)u) << 16;
    return __builtin_bit_cast(float, v);
}
__device__ __forceinline__ float sigm(float x) { return 1.0f / (1.0f + __expf(-x)); }

// async global->LDS, 16B per lane. LDS dest = wave-uniform base + lane*16.
__device__ __forceinline__ void async_ld16(const void* g, void* l) {
    __builtin_amdgcn_global_load_lds(
        (const __attribute__((address_space(1))) unsigned int*)g,
        (__attribute__((address_space(3))) unsigned int*)l, 16, 0, 0);
}

// ---------------- fused prep: weight transposes + casts + ROUTER in one dispatch ----------------
// blocks [0,4096): gup transpose-cast; [4096,6144): dwn transpose-cast;
// [6144,7680): shared-weight casts; [7680,8704): router (independent of weights).
__global__ __launch_bounds__(256) void
prep_all(const float* __restrict__ gup, const float* __restrict__ dwn,
         const float* __restrict__ sgw, const float* __restrict__ suw, const float* __restrict__ sdw,
         unsigned short* __restrict__ w_gup_t, unsigned short* __restrict__ w_dwn_t,
         const float* __restrict__ x, const float* __restrict__ rw,
         float* __restrict__ logits_out, int* __restrict__ cnt,
         int* __restrict__ tok_list, float* __restrict__ score_list, int2* __restrict__ inv) {
    __shared__ float tile[128][65];
    int b = blockIdx.x, tid = threadIdx.x;

    if (b >= 7680) {  // ---- router ----
        int rb = b - 7680;
        int wave = tid >> 6, lane = tid & 63;
        int t = rb * 4 + wave;
        float dot[NE];
#pragma unroll
        for (int e = 0; e < NE; e++) dot[e] = 0.0f;
        const float4* xv = (const float4*)(x + (size_t)t * HID);
        const float4* wv = (const float4*)rw;
#pragma unroll
        for (int j = 0; j < 4; j++) {
            float4 xc = xv[j * 64 + lane];
#pragma unroll
            for (int e = 0; e < NE; e++) {
                float4 wc = wv[e * 256 + j * 64 + lane];
                dot[e] += xc.x * wc.x + xc.y * wc.y + xc.z * wc.z + xc.w * wc.w;
            }
        }
#pragma unroll
        for (int e = 0; e < NE; e++) {
            float v = dot[e];
            for (int m = 1; m < 64; m <<= 1) v += __shfl_xor(v, m, 64);
            dot[e] = v;
        }
        if (lane == 0) {
            float v1 = -1e30f, v2 = -1e30f; int i1 = 0, i2 = 0;
#pragma unroll
            for (int e = 0; e < NE; e++) {
                float v = dot[e];
                logits_out[(size_t)t * NE + e] = v;
                if (v > v1) { v2 = v1; i2 = i1; v1 = v; i1 = e; }
                else if (v > v2) { v2 = v; i2 = e; }
            }
            float s1 = 1.0f / (1.0f + expf(-v1));
            float s2 = 1.0f / (1.0f + expf(-v2));
            int p1 = atomicAdd(&cnt[i1], 1);
            tok_list[i1 * T_TOK + p1] = t; score_list[i1 * T_TOK + p1] = s1;
            int p2 = atomicAdd(&cnt[i2], 1);
            tok_list[i2 * T_TOK + p2] = t; score_list[i2 * T_TOK + p2] = s2;
            inv[t] = make_int2((i1 << 16) | p1, (i2 << 16) | p2);
        }
        return;
    }

    if (b >= 6144) {  // ---- plain casts ----
        int b3 = b - 6144;
        int seg = b3 >> 9, bb = b3 & 511;
        const float* s = (seg == 0) ? sgw : (seg == 1) ? suw : sdw;
        unsigned short* wg8 = w_gup_t + (size_t)NE * 4096 * 1024;
        unsigned short* d = (seg == 0) ? wg8 : (seg == 1) ? (wg8 + 2048 * 1024)
                                             : (w_dwn_t + (size_t)NE * 1024 * 2048);
        int base = bb * 1024 + tid;
#pragma unroll
        for (int p = 0; p < 4; p++) {
            int i = base + p * 256;
            float4 v = ((const float4*)s)[i];
            ushort4 o;
            o.x = f2bf(v.x); o.y = f2bf(v.y); o.z = f2bf(v.z); o.w = f2bf(v.w);
            ((ushort4*)d)[i] = o;
        }
        return;
    }

    const float* W; unsigned short* Wt; int K, N, n0, k0;
    if (b < 4096) {   // gup: [1024][4096] -> [4096][1024]
        int e = b >> 9, t = b & 511;
        W = gup + (size_t)e * 1024 * 4096; Wt = w_gup_t + (size_t)e * 4096 * 1024;
        K = 1024; N = 4096; n0 = (t & 63) * 64; k0 = (t >> 6) * 128;
    } else {          // dwn: [2048][1024] -> [1024][2048]
        int b2 = b - 4096;
        int e = b2 >> 8, t = b2 & 255;
        W = dwn + (size_t)e * 2048 * 1024; Wt = w_dwn_t + (size_t)e * 1024 * 2048;
        K = 2048; N = 1024; n0 = (t & 15) * 64; k0 = (t >> 4) * 128;
    }
    int r = tid >> 4, c = tid & 15;
#pragma unroll
    for (int i = 0; i < 8; i++) {
        int k = i * 16 + r;
        float4 v = *(const float4*)(W + (size_t)(k0 + k) * N + n0 + c * 4);
        tile[k][c * 4 + 0] = v.x; tile[k][c * 4 + 1] = v.y;
        tile[k][c * 4 + 2] = v.z; tile[k][c * 4 + 3] = v.w;
    }
    __syncthreads();
#pragma unroll
    for (int i = 0; i < 4; i++) {
        int n = i * 16 + r;
        ushort8v o;
#pragma unroll
        for (int j = 0; j < 8; j++) o[j] = f2bf(tile[c * 8 + j][n]);
        *(ushort8v*)(Wt + (size_t)(n0 + n) * K + k0 + c * 8) = o;
    }
}

// -------- finalize: pad lists to 128, shared fill, prefix offsets, tile table --------
__global__ void finalize_kernel(const int* __restrict__ cnt, int* __restrict__ offs,
                                int* __restrict__ tiletab,
                                int* __restrict__ tok_list, float* __restrict__ score_list) {
    __shared__ int s_cnt[NE], s_pad[NE];
    int tid = threadIdx.x;
    if (tid == 0) {
        int o = 0, nt = 0;
        for (int e = 0; e < NE1; e++) {
            int c = (e == NE) ? T_TOK : cnt[e];
            int p = (c + 127) & ~127;
            offs[e] = o;
            for (int m = 0; m < (p >> 7); m++) tiletab[nt++] = (e << 8) | m;
            if (e < NE) { s_cnt[e] = c; s_pad[e] = p; }
            o += p;
        }
        for (; nt < MAXT; nt++) tiletab[nt] = -1;
    }
    for (int i = tid; i < T_TOK; i += blockDim.x) {   // shared expert: identity list
        tok_list[NE * T_TOK + i] = i;
        score_list[NE * T_TOK + i] = 1.0f;
    }
    __syncthreads();
    for (int e = 0; e < NE; e++) {
        for (int i = s_cnt[e] + tid; i < s_pad[e]; i += blockDim.x) {
            tok_list[e * T_TOK + i] = 0;
            score_list[e * T_TOK + i] = 0.0f;
        }
    }
}

// -------- gather: xg[slot][k] = bf16(x[tok[slot]][k]) — (MAXT,4) grid, 256-col strips --------
__global__ __launch_bounds__(256) void
gather_kernel(const float* __restrict__ x, const int* __restrict__ tiletab,
              const int* __restrict__ offs, const int* __restrict__ tok_list,
              unsigned short* __restrict__ xg) {
    int tt = tiletab[blockIdx.x];
    if (tt < 0) return;
    int e = tt >> 8, mt = tt & 255;
    size_t rowbase = (size_t)offs[e] + (size_t)mt * 128;
    int col0 = blockIdx.y * 256;
    int tid = threadIdx.x;
    int cc = tid & 15, rl = tid >> 4;
#pragma unroll
    for (int pass = 0; pass < 8; pass++) {
        int r = pass * 16 + rl;
        int tok = tok_list[e * T_TOK + mt * 128 + r];
        const float4* src = (const float4*)(x + (size_t)tok * HID + col0);
        ushort4* dst = (ushort4*)(xg + (rowbase + r) * HID + col0);
#pragma unroll
        for (int p = 0; p < 4; p++) {
            float4 v = src[p * 16 + cc];
            ushort4 o;
            o.x = f2bf(v.x); o.y = f2bf(v.y); o.z = f2bf(v.z); o.w = f2bf(v.w);
            dst[p * 16 + cc] = o;
        }
    }
}

// ======== GEMM1 pipelined: wave-private LDS, barrier-free K-loop, vmcnt sync ========
// 512 thr = 8 waves; wave tile 64M x (32 gate + 32 up); BK=32, double-buffered.
// Each wave stages ONLY the LDS it reads -> s_waitcnt vmcnt(8) is a complete fence.
__global__ __launch_bounds__(512, 2) void
moe_g1p(const unsigned short* __restrict__ xg, const unsigned short* __restrict__ wg_t,
        const int* __restrict__ tiletab, const int* __restrict__ offs,
        const float* __restrict__ score_list, unsigned short* __restrict__ h) {
    int tt = tiletab[blockIdx.y];
    if (tt < 0) return;
    int e = tt >> 8, mt = tt & 255;
    int nt = blockIdx.x;                  // 0..15, 128 i-cols per block

    // 8 waves x 2 bufs x 4096 shorts (A:2048 | Bg:1024 | Bu:1024) = 128 KB
    __shared__ unsigned short lds[8 * 2 * 4096];
    __shared__ float s_sc[128];

    int tid = threadIdx.x, lane = tid & 63, wid = tid >> 6;
    int wm = wid >> 2, wn = wid & 3;
    size_t rowbase = (size_t)offs[e] + (size_t)mt * 128;

    if (tid < 128) s_sc[tid] = score_list[e * T_TOK + mt * 128 + tid];
    __syncthreads();   // one barrier total (epilogue reads s_sc)

    const unsigned short* wg = wg_t + (size_t)e * (4096u * 1024u);
    int i0 = nt * 128 + wn * 32;

    // staging source pointers: LDS[row][c] holds global k-chunk (c ^ (row&3))
    const unsigned short* pA[4];
    const unsigned short* pBg[2];
    const unsigned short* pBu[2];
#pragma unroll
    for (int j = 0; j < 4; j++) {
        int cid = j * 64 + lane;
        int row = cid >> 2, c = cid & 3;
        pA[j] = xg + (rowbase + wm * 64 + row) * HID + (c ^ (row & 3)) * 8;
    }
#pragma unroll
    for (int j = 0; j < 2; j++) {
        int cid = j * 64 + lane;
        int n = cid >> 2, c = cid & 3;
        pBg[j] = wg + (size_t)(i0 + n) * HID + (c ^ (n & 3)) * 8;
        pBu[j] = wg + (size_t)(INTER + i0 + n) * HID + (c ^ (n & 3)) * 8;
    }
    unsigned short* wl = lds + wid * 2 * 4096;   // wave base; buf b at + b*4096

    f32x4 accg[4][2], accu[4][2];
#pragma unroll
    for (int i = 0; i < 4; i++)
#pragma unroll
        for (int j = 0; j < 2; j++) { accg[i][j] = (f32x4)(0.0f); accu[i][j] = (f32x4)(0.0f); }

    int q = lane >> 4, ml = lane & 15;
    int csl = (q ^ (ml & 3)) * 8;   // fragment read slot offset (shorts)

#define STAGE(buf, kE)                                                          \
    {                                                                           \
        unsigned short* dst = wl + (buf) * 4096;                                \
        _Pragma("unroll")                                                       \
        for (int j = 0; j < 4; j++) async_ld16(pA[j] + (kE), dst + j * 512);    \
        _Pragma("unroll")                                                       \
        for (int j = 0; j < 2; j++) {                                           \
            async_ld16(pBg[j] + (kE), dst + 2048 + j * 512);                    \
            async_ld16(pBu[j] + (kE), dst + 3072 + j * 512);                    \
        }                                                                       \
    }

#define COMPUTE(buf)                                                            \
    {                                                                           \
        const unsigned short* B = wl + (buf) * 4096;                            \
        short8 af[4], bg[2], bu[2];                                             \
        _Pragma("unroll")                                                       \
        for (int mi = 0; mi < 4; mi++)                                          \
            af[mi] = *(const short8*)(B + (mi * 16 + ml) * 32 + csl);           \
        _Pragma("unroll")                                                       \
        for (int ni = 0; ni < 2; ni++) {                                        \
            bg[ni] = *(const short8*)(B + 2048 + (ni * 16 + ml) * 32 + csl);    \
            bu[ni] = *(const short8*)(B + 3072 + (ni * 16 + ml) * 32 + csl);    \
        }                                                                       \
        _Pragma("unroll")                                                       \
        for (int mi = 0; mi < 4; mi++)                                          \
            _Pragma("unroll")                                                   \
            for (int ni = 0; ni < 2; ni++) {                                    \
                accg[mi][ni] = __builtin_amdgcn_mfma_f32_16x16x32_bf16(af[mi], bg[ni], accg[mi][ni], 0, 0, 0); \
                accu[mi][ni] = __builtin_amdgcn_mfma_f32_16x16x32_bf16(af[mi], bu[ni], accu[mi][ni], 0, 0, 0); \
            }                                                                   \
    }

    STAGE(0, 0)
    for (int it = 0; it < 31; ++it) {
        STAGE((it + 1) & 1, (it + 1) * 32)
        asm volatile("s_waitcnt vmcnt(8)" ::: "memory");
        COMPUTE(it & 1)
    }
    asm volatile("s_waitcnt vmcnt(0)" ::: "memory");
    COMPUTE(1)
#undef STAGE
#undef COMPUTE

#pragma unroll
    for (int mi = 0; mi < 4; mi++)
#pragma unroll
        for (int ni = 0; ni < 2; ni++)
#pragma unroll
            for (int r = 0; r < 4; r++) {
                int m = wm * 64 + mi * 16 + q * 4 + r;
                int i = i0 + ni * 16 + ml;
                float s = s_sc[m];
                float g = accg[mi][ni][r] * s;
                float u = accu[mi][ni][r] * s;
                h[(rowbase + m) * INTER + i] = f2bf(u * g * sigm(g));
            }
}

// ---------------- GEMM2 (R4 config, verified): 128M x 128N -> dense r_out ----------------
__global__ __launch_bounds__(256) void
moe_g2(const unsigned short* __restrict__ h, const unsigned short* __restrict__ wd_t,
       const int* __restrict__ tiletab, const int* __restrict__ offs,
       unsigned short* __restrict__ r_out) {
    int tt = tiletab[blockIdx.y];
    if (tt < 0) return;
    int e = tt >> 8, mt = tt & 255;
    int nt = blockIdx.x;  // 0..7, 128 H-cols

    __shared__ unsigned short As[128 * BK];
    __shared__ unsigned short Bs[128 * BK];

    int tid = threadIdx.x, lane = tid & 63;
    int wid = tid >> 6, wm = wid >> 1, wn = wid & 1;
    size_t rowbase = (size_t)offs[e] + (size_t)mt * 128;

    const unsigned short* wd = wd_t + (size_t)e * (1024u * 2048u);
    int rsub = tid >> 3;
    int csw = (tid & 7) ^ (rsub & 7);
    const unsigned short* pA[4];
    const unsigned short* pB[4];
#pragma unroll
    for (int i = 0; i < 4; i++) {
        pA[i] = h + (rowbase + i * 32 + rsub) * INTER + csw * 8;
        pB[i] = wd + (size_t)(nt * 128 + i * 32 + rsub) * INTER + csw * 8;
    }
    unsigned short* lA = As + tid * 8;
    unsigned short* lB = Bs + tid * 8;

    f32x4 acc[4][4];
#pragma unroll
    for (int i = 0; i < 4; i++)
#pragma unroll
        for (int j = 0; j < 4; j++) acc[i][j] = (f32x4)(0.0f);

    int mrow = lane & 15, qq = lane >> 4, x7 = lane & 7;
    for (int k0 = 0; k0 < INTER; k0 += BK) {
#pragma unroll
        for (int i = 0; i < 4; i++) {
            async_ld16(pA[i] + k0, lA + i * 2048);
            async_ld16(pB[i] + k0, lB + i * 2048);
        }
        __syncthreads();
#pragma unroll
        for (int ksub = 0; ksub < 2; ksub++) {
            int ch = ((ksub * 4 + qq) ^ x7) * 8;
            short8 af[4], bf_[4];
#pragma unroll
            for (int mi = 0; mi < 4; mi++)
                af[mi] = *(const short8*)(As + (wm * 64 + mi * 16 + mrow) * BK + ch);
#pragma unroll
            for (int ni = 0; ni < 4; ni++)
                bf_[ni] = *(const short8*)(Bs + (wn * 64 + ni * 16 + mrow) * BK + ch);
#pragma unroll
            for (int mi = 0; mi < 4; mi++)
#pragma unroll
                for (int ni = 0; ni < 4; ni++)
                    acc[mi][ni] = __builtin_amdgcn_mfma_f32_16x16x32_bf16(af[mi], bf_[ni], acc[mi][ni], 0, 0, 0);
        }
        __syncthreads();
    }
#pragma unroll
    for (int mi = 0; mi < 4; mi++)
#pragma unroll
        for (int ni = 0; ni < 4; ni++)
#pragma unroll
            for (int r = 0; r < 4; r++) {
                int m = wm * 64 + mi * 16 + (lane >> 4) * 4 + r;
                int n = nt * 128 + wn * 64 + ni * 16 + (lane & 15);
                r_out[(rowbase + m) * HID + n] = f2bf(acc[mi][ni][r]);
            }
}

// ---------------- combine: out[t] = shared + two routed contributions ----------------
__global__ void combine_kernel(const unsigned short* __restrict__ r_out,
                               const int2* __restrict__ inv, const int* __restrict__ offs,
                               float* __restrict__ out) {
    int t = blockIdx.x, tid = threadIdx.x;
    int2 iv = inv[t];
    size_t r1 = (size_t)(offs[iv.x >> 16] + (iv.x & 0xffff)) * HID;
    size_t r2 = (size_t)(offs[iv.y >> 16] + (iv.y & 0xffff)) * HID;
    size_t rs = (size_t)(offs[NE] + t) * HID;
    int i = tid * 4;
    ushort4 a = *(const ushort4*)(r_out + r1 + i);
    ushort4 b = *(const ushort4*)(r_out + r2 + i);
    ushort4 c = *(const ushort4*)(r_out + rs + i);
    float4 o;
    o.x = bf2f(a.x) + bf2f(b.x) + bf2f(c.x);
    o.y = bf2f(a.y) + bf2f(b.y) + bf2f(c.y);
    o.z = bf2f(a.z) + bf2f(b.z) + bf2f(c.z);
    o.w = bf2f(a.w) + bf2f(b.w) + bf2f(c.w);
    *(float4*)(out + (size_t)t * HID + i) = o;
}

extern "C" void kernel_launch(void* const* d_in, const int* in_sizes, int n_in,
                              void* d_out, int out_size, void* d_ws, size_t ws_size,
                              hipStream_t stream) {
    const float* x   = (const float*)d_in[0];
    const float* rw  = (const float*)d_in[1];
    const float* gup = (const float*)d_in[2];
    const float* dwn = (const float*)d_in[3];
    const float* sgw = (const float*)d_in[4];
    const float* suw = (const float*)d_in[5];
    const float* sdw = (const float*)d_in[6];
    float* out = (float*)d_out;
    float* logits = out + (size_t)T_TOK * HID;

    char* ws = (char*)d_ws;
    int*   cnt        = (int*)(ws + 0);
    int*   offs       = (int*)(ws + 64);
    int*   tiletab    = (int*)(ws + 128);
    int2*  inv        = (int2*)(ws + 4096);
    int*   tok_list   = (int*)(ws + 65536);
    float* score_list = (float*)(ws + 212992);
    unsigned short* w_gup_t = (unsigned short*)(ws + 524288);     // 75497472
    unsigned short* w_dwn_t = (unsigned short*)(ws + 76021760);   // 37748736
    unsigned short* xg      = (unsigned short*)(ws + 113770496);  // 27262976
    unsigned short* h       = (unsigned short*)(ws + 141033472);  // 54525952
    unsigned short* r_out   = (unsigned short*)(ws + 195559424);  // 27262976

    hipMemsetAsync(cnt, 0, NE * sizeof(int), stream);

    prep_all<<<8704, 256, 0, stream>>>(gup, dwn, sgw, suw, sdw, w_gup_t, w_dwn_t,
                                       x, rw, logits, cnt, tok_list, score_list, inv);
    finalize_kernel<<<1, 256, 0, stream>>>(cnt, offs, tiletab, tok_list, score_list);
    {
        dim3 gg(MAXT, 4);
        gather_kernel<<<gg, 256, 0, stream>>>(x, tiletab, offs, tok_list, xg);
    }

    dim3 g1(16, MAXT);   // 16 nt x m-tiles, 512 thr, 1 block/CU
    moe_g1p<<<g1, 512, 0, stream>>>(xg, w_gup_t, tiletab, offs, score_list, h);
    dim3 g2(HID / 128, MAXT);
    moe_g2<<<g2, 256, 0, stream>>>(h, w_dwn_t, tiletab, offs, r_out);
    combine_kernel<<<T_TOK, 256, 0, stream>>>(r_out, inv, offs, out);
}